// Round 21
// baseline (561.663 us; speedup 1.0000x reference)
//
#include <hip/hip_runtime.h>

typedef __attribute__((ext_vector_type(4))) float f32x4;
typedef __attribute__((ext_vector_type(4))) unsigned int u32x4;
typedef __attribute__((ext_vector_type(8))) short s16x8;
typedef __attribute__((ext_vector_type(8))) _Float16 f16x8;

#define N_NODES 65536
#define GNPG 1024
#define FDIM 64
#define HDIM 128
#define KNN 16
#define JT 64      // knn j-tile
#define DSTR 68    // knn key LDS row stride (u32)
#define SCAND 20   // per-(sub,jhalf) candidate list
#define STKC 6     // per-lane survivor stack depth (u32 keys)
#define NEDGE (N_NODES * KNN)
#define NT (NEDGE / 64)

// Per-node precompute (blocks 0..1023) + W2 frag prep (block 1024) + Wc frag prep (1025).
__global__ void prep_node_k(const float* __restrict__ x, float* __restrict__ sq,
                            double* __restrict__ sq64, _Float16* __restrict__ xf,
                            const float* __restrict__ W2, _Float16* __restrict__ w2f,
                            const float* __restrict__ W1, _Float16* __restrict__ w1cf) {
  if (blockIdx.x >= 1024) {
    int tid = threadIdx.x;
    if (blockIdx.x == 1024) {
      for (int idx = tid; idx < 8 * 4 * 64 * 8; idx += 256) {
        int j = idx & 7, l = (idx >> 3) & 63, ks = (idx >> 9) & 3, ct = idx >> 11;
        int k = 8 * (l >> 4) + j + 32 * ks, col = ct * 16 + (l & 15);
        w2f[idx] = (_Float16)W2[k * 128 + col];
      }
    } else {
      // Wc = [W1_top - W1_bot | W1_bot] (64x256) in B-frag order (16 ct x 2 ks).
      for (int idx = tid; idx < 16 * 2 * 64 * 8; idx += 256) {
        int j = idx & 7, l = (idx >> 3) & 63, ks = (idx >> 9) & 1, ct = idx >> 10;
        int k = 8 * (l >> 4) + j + 32 * ks, col = ct * 16 + (l & 15);
        float v = (col < 128) ? (W1[k * 128 + col] - W1[(k + 64) * 128 + col])
                              : W1[(k + 64) * 128 + (col - 128)];
        w1cf[idx] = (_Float16)v;
      }
    }
    return;
  }
  int t = blockIdx.x * 256 + threadIdx.x;
  int n = t >> 2, q = t & 3;
  const f32x4* xp = (const f32x4*)(x + (size_t)n * FDIM + q * 16);
  double s = 0;
  f16x8 h0, h1;
#pragma unroll
  for (int c8 = 0; c8 < 2; ++c8) {
    f32x4 a = xp[2 * c8], b = xp[2 * c8 + 1];
    f16x8 h;
#pragma unroll
    for (int e = 0; e < 4; ++e) {
      h[e] = (_Float16)a[e];
      h[4 + e] = (_Float16)b[e];
      s = fma((double)a[e], (double)a[e], s);
      s = fma((double)b[e], (double)b[e], s);
    }
    if (c8 == 0) h0 = h; else h1 = h;
  }
  *(f16x8*)(xf + (size_t)n * FDIM + q * 16) = h0;
  *(f16x8*)(xf + (size_t)n * FDIM + q * 16 + 8) = h1;
  s += __shfl_xor(s, 1);
  s += __shfl_xor(s, 2);
  if (q == 0) { sq64[n] = s; sq[n] = (float)s; }
}

// GEMM1 via fp16 MFMA: PQ16 = xf @ Wc (+b1 on cols>=128). 128 nodes/block, 4 waves.
__global__ __launch_bounds__(256) void prep_pq_k(const _Float16* __restrict__ xf,
                                                 const _Float16* __restrict__ w1cf,
                                                 const float* __restrict__ b1,
                                                 _Float16* __restrict__ PQ16) {
  __shared__ __attribute__((aligned(16))) _Float16 wcL[16384];   // 32KB
  int tid = threadIdx.x, lane = tid & 63, wave = tid >> 6;
  for (int i = tid; i < 2048; i += 256)
    *(f16x8*)(wcL + i * 8) = *(const f16x8*)(w1cf + i * 8);
  int rbase = blockIdx.x * 128 + wave * 32;
  f16x8 af[2][2];
#pragma unroll
  for (int rt = 0; rt < 2; ++rt)
#pragma unroll
    for (int ks = 0; ks < 2; ++ks) {
      size_t off = (size_t)(rbase + rt * 16 + (lane & 15)) * FDIM + (lane >> 4) * 8 + 32 * ks;
      af[rt][ks] = *(const f16x8*)(xf + off);
    }
  __syncthreads();
  f32x4 acc[2][16];
#pragma unroll
  for (int rt = 0; rt < 2; ++rt)
#pragma unroll
    for (int ct = 0; ct < 16; ++ct) acc[rt][ct] = (f32x4){0.f, 0.f, 0.f, 0.f};
#pragma unroll
  for (int ks = 0; ks < 2; ++ks)
#pragma unroll
    for (int ct = 0; ct < 16; ++ct) {
      f16x8 b = *(const f16x8*)(wcL + ((ct * 2 + ks) * 64 + lane) * 8);
#pragma unroll
      for (int rt = 0; rt < 2; ++rt)
        acc[rt][ct] = __builtin_amdgcn_mfma_f32_16x16x32_f16(af[rt][ks], b, acc[rt][ct], 0, 0, 0);
    }
  float b1r[16];
#pragma unroll
  for (int ct = 0; ct < 16; ++ct)
    b1r[ct] = (ct >= 8) ? b1[(ct - 8) * 16 + (lane & 15)] : 0.f;
#pragma unroll
  for (int rt = 0; rt < 2; ++rt)
#pragma unroll
    for (int ct = 0; ct < 16; ++ct) {
      int col = ct * 16 + (lane & 15);
#pragma unroll
      for (int r = 0; r < 4; ++r) {
        int row = rbase + rt * 16 + (lane >> 4) * 4 + r;
        PQ16[(size_t)row * 256 + col] = (_Float16)(acc[rt][ct][r] + b1r[ct]);
      }
    }
}

// KNN stage 1: block = 128 centers x HALF the j-range (1024 blocks, 4/CU). fp16 MFMA
// distances -> biased-positive monotone u32 keys -> streaming survivor-stack scan with
// wave-joint u32 min/max ladder. Writes the sorted 20-key list per (center,sub,jhalf).
__global__ __launch_bounds__(256) void knn1_k(const _Float16* __restrict__ xf,
                                              const float* __restrict__ sq,
                                              unsigned* __restrict__ candk) {
  __shared__ float sq_l[GNPG];
  __shared__ __attribute__((aligned(16))) _Float16 bfL[512 * 8];
  __shared__ __attribute__((aligned(16))) unsigned keyL[128 * DSTR];
  __shared__ __attribute__((aligned(16))) unsigned stk[STKC * 256];
  int tid = threadIdx.x, lane = tid & 63, wave = tid >> 6;
  int g = blockIdx.x >> 4;
  int wb = blockIdx.x & 15;
  int rb = (wb >> 1) * 128;
  int jh = wb & 1;
  int jbase = jh * 512;
  const _Float16* xfg = xf + (size_t)g * GNPG * FDIM;
  for (int i = tid; i < GNPG; i += 256) sq_l[i] = sq[g * GNPG + i] + 0.5f;  // d' = d + 1 > 0
  f16x8 af[2][2];
#pragma unroll
  for (int rt = 0; rt < 2; ++rt)
#pragma unroll
    for (int ks = 0; ks < 2; ++ks) {
      size_t off = (size_t)(rb + wave * 32 + rt * 16 + (lane & 15)) * FDIM + (lane >> 4) * 8 + 32 * ks;
      af[rt][ks] = *(const f16x8*)(xfg + off);
    }
  unsigned dl[SCAND];
#pragma unroll
  for (int q = 0; q < SCAND; ++q) dl[q] = 0xFFFFFFFFu;
  int c = tid >> 1, sub = tid & 1;
  int sp = 0;
  for (int jt = 0; jt < 512 / JT; ++jt) {
#pragma unroll
    for (int s2 = tid; s2 < 512; s2 += 256) {
      int ct = s2 >> 7, ks = (s2 >> 6) & 1, l = s2 & 63;
      size_t goff = (size_t)(jbase + jt * JT + ct * 16 + (l & 15)) * FDIM + (l >> 4) * 8 + 32 * ks;
      *(f16x8*)(bfL + s2 * 8) = *(const f16x8*)(xfg + goff);
    }
    __syncthreads();
    f32x4 acc[2][4];
#pragma unroll
    for (int rt = 0; rt < 2; ++rt)
#pragma unroll
      for (int ct = 0; ct < 4; ++ct) acc[rt][ct] = (f32x4){0.f, 0.f, 0.f, 0.f};
#pragma unroll
    for (int ks = 0; ks < 2; ++ks)
#pragma unroll
      for (int ct = 0; ct < 4; ++ct) {
        f16x8 bfr = *(const f16x8*)(bfL + ((ct * 2 + ks) * 64 + lane) * 8);
#pragma unroll
        for (int rt = 0; rt < 2; ++rt)
          acc[rt][ct] = __builtin_amdgcn_mfma_f32_16x16x32_f16(af[rt][ks], bfr, acc[rt][ct], 0, 0, 0);
      }
#pragma unroll
    for (int rt = 0; rt < 2; ++rt)
#pragma unroll
      for (int ct = 0; ct < 4; ++ct) {
        int coltl = ct * 16 + (lane & 15);
        int jlg = jbase + jt * JT + coltl;
        float sqj = sq_l[jlg];
#pragma unroll
        for (int r = 0; r < 4; ++r) {
          int row = wave * 32 + rt * 16 + (lane >> 4) * 4 + r;
          float d = sq_l[rb + row] + sqj - 2.f * acc[rt][ct][r];   // > 0 (biased)
          unsigned key = (__float_as_uint(d) & 0xFFFFFC00u) | (unsigned)jlg;
          if (rb + row == jlg) key = 0xFFFFFFFFu;
          keyL[row * DSTR + coltl] = key;
        }
      }
    __syncthreads();
    const unsigned* kp = keyL + c * DSTR + sub * 32;
#pragma unroll 2
    for (int i = 0; i < 8; ++i) {
      if (__any(sp > STKC - 4)) {
        while (__any(sp > 0)) {
          if (sp > 0) {
            --sp;
            unsigned k = stk[sp * 256 + tid];
            if (k < dl[SCAND - 1]) {
              dl[SCAND - 1] = k;
#pragma unroll
              for (int p = SCAND - 1; p >= 1; --p) {
                unsigned mn = min(dl[p - 1], dl[p]);
                unsigned mx = max(dl[p - 1], dl[p]);
                dl[p - 1] = mn; dl[p] = mx;
              }
            }
          }
        }
      }
      u32x4 v = *(const u32x4*)(kp + i * 4);
#pragma unroll
      for (int e = 0; e < 4; ++e) {
        stk[sp * 256 + tid] = v[e];
        sp += (v[e] < dl[SCAND - 1]) ? 1 : 0;
      }
    }
  }
  while (__any(sp > 0)) {
    if (sp > 0) {
      --sp;
      unsigned k = stk[sp * 256 + tid];
      if (k < dl[SCAND - 1]) {
        dl[SCAND - 1] = k;
#pragma unroll
        for (int p = SCAND - 1; p >= 1; --p) {
          unsigned mn = min(dl[p - 1], dl[p]);
          unsigned mx = max(dl[p - 1], dl[p]);
          dl[p - 1] = mn; dl[p] = mx;
        }
      }
    }
  }
  int nglob = g * GNPG + rb + c;
  unsigned* ok = candk + (((size_t)nglob * 2 + sub) * 2 + jh) * SCAND;
#pragma unroll
  for (int q = 0; q < SCAND; ++q) ok[q] = dl[q];
}

// KNN stage 2: 2 threads/center. Each thread 2-pointer-merges its sub's two sorted
// jhalf key-lists -> top-20-of-union (provably = single-scan top-20), then f64-rescores
// the 20 (unroll-1, immediate-consume loads), 16-deep (d64,idx) ladder, LDS pair merge.
__global__ __launch_bounds__(256) void knn2_k(const float* __restrict__ x,
                                              const double* __restrict__ sq64,
                                              const unsigned* __restrict__ candk,
                                              int* __restrict__ nbr, int* __restrict__ counts) {
  __shared__ double md[2][128][17];
  __shared__ unsigned short mi[2][128][17];
  int tid = threadIdx.x, c_local = tid >> 1, sub = tid & 1;
  int n = blockIdx.x * 128 + c_local;
  int gbase = n & ~(GNPG - 1);
  const unsigned* ka = candk + ((size_t)n * 2 + sub) * 2 * SCAND;
  const unsigned* kb = ka + SCAND;
  unsigned ml[SCAND];
  {
    int pa = 0, pb = 0;
#pragma unroll
    for (int q = 0; q < SCAND; ++q) {
      unsigned va = ka[pa], vb = kb[pb];
      bool tb = vb < va;
      ml[q] = tb ? vb : va;
      pa += !tb; pb += tb;
    }
  }
  f32x4 xi[16];
  const f32x4* xp = (const f32x4*)(x + (size_t)n * FDIM);
#pragma unroll
  for (int f = 0; f < 16; ++f) xi[f] = xp[f];
  double sq64i = sq64[n];
  double dl[KNN]; int il[KNN];
#pragma unroll
  for (int q = 0; q < KNN; ++q) { dl[q] = 1.0e300; il[q] = 0x7FFFFFFF; }
#pragma unroll 1
  for (int t = 0; t < SCAND; ++t) {
    int jl = (int)(ml[t] & 1023u);
    int j = gbase + jl;
    const f32x4* xj = (const f32x4*)(x + (size_t)j * FDIM);
    double t0 = 0, t1 = 0, t2 = 0, t3 = 0;
#pragma unroll
    for (int f = 0; f < 16; ++f) {
      f32x4 a = xi[f], b = xj[f];
      t0 = fma((double)a[0], (double)b[0], t0);
      t1 = fma((double)a[1], (double)b[1], t1);
      t2 = fma((double)a[2], (double)b[2], t2);
      t3 = fma((double)a[3], (double)b[3], t3);
    }
    double d = sq64i + sq64[j] - 2.0 * ((t0 + t1) + (t2 + t3));
    bool ins = (d < dl[KNN - 1]) || (d == dl[KNN - 1] && jl < il[KNN - 1]);
    if (ins) {
      dl[KNN - 1] = d; il[KNN - 1] = jl;
#pragma unroll
      for (int p = KNN - 1; p >= 1; --p) {
        double a0 = dl[p - 1], a1 = dl[p];
        int b0 = il[p - 1], b1v = il[p];
        bool cc = (a1 < a0) || (a1 == a0 && b1v < b0);
        dl[p - 1] = cc ? a1 : a0; dl[p] = cc ? a0 : a1;
        il[p - 1] = cc ? b1v : b0; il[p] = cc ? b0 : b1v;
      }
    }
  }
#pragma unroll
  for (int q = 0; q < KNN; ++q) {
    md[sub][c_local][q] = dl[q];
    mi[sub][c_local][q] = (unsigned short)il[q];
  }
  __syncthreads();
  if (sub == 0) {
    int pa = 0, pb = 0;
    for (int q = 0; q < KNN; ++q) {
      double da = md[0][c_local][pa]; int ia = mi[0][c_local][pa];
      double db = md[1][c_local][pb]; int ib = mi[1][c_local][pb];
      bool tb = (db < da) || (db == da && ib < ia);
      int iw = tb ? ib : ia;
      pa += !tb; pb += tb;
      int gidx = gbase + iw;
      nbr[(size_t)n * KNN + q] = gidx;
      atomicAdd(&counts[gidx], 1);
    }
  }
}

// Block-wide scan: 1024 threads x 64 counts, shfl wave-scan + wave partials.
__global__ void scan_k(const int* __restrict__ counts, int* __restrict__ cursor) {
  __shared__ int wsum[16];
  int t = threadIdx.x;
  int base = t * 64;
  const int4* cp = (const int4*)(counts + base);
  int s = 0;
#pragma unroll
  for (int i = 0; i < 16; ++i) { int4 v = cp[i]; s += v.x + v.y + v.z + v.w; }
  int lane = t & 63, wv = t >> 6;
  int pre = s;
#pragma unroll
  for (int ofs = 1; ofs < 64; ofs <<= 1) {
    int o = __shfl_up(pre, ofs);
    if (lane >= ofs) pre += o;
  }
  if (lane == 63) wsum[wv] = pre;
  __syncthreads();
  if (t == 0) {
    int run = 0;
#pragma unroll
    for (int i = 0; i < 16; ++i) { int v = wsum[i]; wsum[i] = run; run += v; }
  }
  __syncthreads();
  int run = wsum[wv] + pre - s;
#pragma unroll
  for (int i = 0; i < 16; ++i) {
    int4 v = cp[i];
    cursor[base + 4 * i] = run; run += v.x;
    cursor[base + 4 * i + 1] = run; run += v.y;
    cursor[base + 4 * i + 2] = run; run += v.z;
    cursor[base + 4 * i + 3] = run; run += v.w;
  }
}

__global__ void scatter_k(const int* __restrict__ nbr, int* __restrict__ cursor,
                          int* __restrict__ srow, int* __restrict__ scol) {
  int e = blockIdx.x * 256 + threadIdx.x;
  int r = nbr[e], c = e >> 4;
  int pos = atomicAdd(&cursor[r], 1);
  srow[pos] = r; scol[pos] = c;
}

// gemm2 (r12 proven form + srowL staging): 64-edge tiles / 256 threads; fp16 PQ gather
// with 2-deep register prefetch; 16KB LDS (fp16 A tile aliases fp16 h2, barrier-sep);
// h2 swizzled (row&12)<<3; serial 32-edge segmented reduce per (col, half) -> atomicAdd.
__global__ __launch_bounds__(256) void gemm2_k(const _Float16* __restrict__ PQ16,
                                               const int* __restrict__ srow, const int* __restrict__ scol,
                                               const _Float16* __restrict__ w2f,
                                               const float* __restrict__ b2,
                                               float* __restrict__ out) {
  __shared__ __attribute__((aligned(16))) char smem[16384];
  __shared__ int srowL[64];
  int tid = threadIdx.x, lane = tid & 63, wave = tid >> 6;
  int cg = wave & 1, eg = wave >> 1;
  f16x8 wf[4][4];
#pragma unroll
  for (int ct = 0; ct < 4; ++ct)
#pragma unroll
    for (int ks = 0; ks < 4; ++ks)
      wf[ct][ks] = *(const f16x8*)(w2f + ((((cg * 4 + ct) * 4 + ks) * 64 + lane) * 8));
  float b2r[4];
#pragma unroll
  for (int ct = 0; ct < 4; ++ct) b2r[ct] = b2[cg * 64 + ct * 16 + (lane & 15)];

  int e_in = tid >> 2, qq = tid & 3;
  f16x8 pf[8];
  int prow;
  {
    int e = blockIdx.x * 64 + e_in;
    prow = srow[e];
    int colc = scol[e];
    const f16x8* Pp = (const f16x8*)(PQ16 + (size_t)prow * 256 + qq * 32);
    const f16x8* Qp = (const f16x8*)(PQ16 + (size_t)colc * 256 + 128 + qq * 32);
#pragma unroll
    for (int i = 0; i < 4; ++i) { pf[i] = Pp[i]; pf[4 + i] = Qp[i]; }
  }
  for (int tile = blockIdx.x; tile < NT; tile += gridDim.x) {
    if (qq == 0) srowL[e_in] = prow;
#pragma unroll
    for (int i = 0; i < 4; ++i) {
      f16x8 hv;
#pragma unroll
      for (int e = 0; e < 8; ++e) {
        float sv = (float)pf[i][e] + (float)pf[4 + i][e];
        hv[e] = (_Float16)(sv > 0.f ? sv : 0.f);
      }
      int byteoff = e_in * 256 + ((2 * (qq * 32 + i * 8)) ^ ((e_in & 7) << 4));
      *(f16x8*)(smem + byteoff) = hv;
    }
    int ntile = tile + gridDim.x;
    if (ntile < NT) {
      int e = ntile * 64 + e_in;
      prow = srow[e];
      int colc = scol[e];
      const f16x8* Pp = (const f16x8*)(PQ16 + (size_t)prow * 256 + qq * 32);
      const f16x8* Qp = (const f16x8*)(PQ16 + (size_t)colc * 256 + 128 + qq * 32);
#pragma unroll
      for (int i = 0; i < 4; ++i) { pf[i] = Pp[i]; pf[4 + i] = Qp[i]; }
    }
    __syncthreads();   // A + srowL visible
    f32x4 acc[2][4];
#pragma unroll
    for (int rt = 0; rt < 2; ++rt)
#pragma unroll
      for (int ct = 0; ct < 4; ++ct) acc[rt][ct] = (f32x4){0.f, 0.f, 0.f, 0.f};
#pragma unroll
    for (int rt = 0; rt < 2; ++rt) {
      int rowL = eg * 32 + rt * 16 + (lane & 15);
#pragma unroll
      for (int ks = 0; ks < 4; ++ks) {
        int byteoff = rowL * 256 + ((16 * (lane >> 4) + 64 * ks) ^ ((rowL & 7) << 4));
        f16x8 a = *(const f16x8*)(smem + byteoff);
#pragma unroll
        for (int ct = 0; ct < 4; ++ct)
          acc[rt][ct] = __builtin_amdgcn_mfma_f32_16x16x32_f16(a, wf[ct][ks], acc[rt][ct], 0, 0, 0);
      }
    }
    __syncthreads();   // A consumed; smem becomes h2 (fp16 [64][128], (row&12)<<3 swizzle)
#pragma unroll
    for (int rt = 0; rt < 2; ++rt)
#pragma unroll
      for (int ct = 0; ct < 4; ++ct) {
        int col = cg * 64 + ct * 16 + (lane & 15);
#pragma unroll
        for (int r = 0; r < 4; ++r) {
          int row_in = eg * 32 + rt * 16 + (lane >> 4) * 4 + r;
          float v = acc[rt][ct][r] + b2r[ct];
          v = v > 0.f ? v : 0.f;
          int byteoff = row_in * 256 + ((2 * col) ^ ((row_in & 12) << 3));
          *(_Float16*)(smem + byteoff) = (_Float16)v;
        }
      }
    __syncthreads();   // h2 visible
    {
      int col = tid & 127, estart = (tid >> 7) * 32;
      float a = 0.f;
      int prev = srowL[estart];
#pragma unroll 8
      for (int e2 = estart; e2 < estart + 32; ++e2) {
        int r2 = srowL[e2];
        if (r2 != prev) { atomicAdd(out + (size_t)prev * 128 + col, a); a = 0.f; prev = r2; }
        int byteoff = e2 * 256 + ((2 * col) ^ ((e2 & 12) << 3));
        a += (float)*(const _Float16*)(smem + byteoff);
      }
      atomicAdd(out + (size_t)prev * 128 + col, a);
    }
    __syncthreads();   // h2 + srowL consumed before next stage write
  }
}

__global__ void final_k(float* __restrict__ out, const int* __restrict__ counts) {
  for (int i = blockIdx.x * 256 + threadIdx.x; i < N_NODES * 32; i += gridDim.x * 256) {
    f32x4 v = ((f32x4*)out)[i];
    int n = i >> 5;
    int c = counts[n];
    float inv = 1.0f / (float)(c > 0 ? c : 1);
    v[0] *= inv; v[1] *= inv; v[2] *= inv; v[3] *= inv;
    ((f32x4*)out)[i] = v;
  }
}

extern "C" void kernel_launch(void* const* d_in, const int* in_sizes, int n_in,
                              void* d_out, int out_size, void* d_ws, size_t ws_size,
                              hipStream_t stream) {
  const float* x = (const float*)d_in[0];
  const float* W1 = (const float*)d_in[2];
  const float* b1 = (const float*)d_in[3];
  const float* W2 = (const float*)d_in[4];
  const float* b2 = (const float*)d_in[5];
  float* out = (float*)d_out;
  char* ws = (char*)d_ws;

  // No aliasing: PQ16 [0,32M); xf [32M,40M); candk [40M,61M).
  _Float16* PQ16 = (_Float16*)(ws + 0);                    // 33,554,432 B
  _Float16* xf = (_Float16*)(ws + 33554432);               //  8,388,608 B
  unsigned* candk = (unsigned*)(ws + 41943040);            // 20,971,520 B (end 62,914,560)
  float* sq = (float*)(ws + 67108864);                     //    262,144 B
  int* nbr = (int*)(ws + 67371008);                        //  4,194,304 B
  int* counts = (int*)(ws + 71565312);                     //    262,144 B
  int* cursor = (int*)(ws + 71827456);                     //    262,144 B
  int* srow = (int*)(ws + 72089600);                       //  4,194,304 B
  int* scol = (int*)(ws + 76283904);                       //  4,194,304 B
  _Float16* w2f = (_Float16*)(ws + 80478208);              //     32,768 B
  _Float16* w1cf = (_Float16*)(ws + 80510976);             //     32,768 B
  double* sq64 = (double*)(ws + 80543744);                 //    524,288 B  (end 81,068,032)

  hipMemsetAsync(d_out, 0, (size_t)out_size * sizeof(float), stream);
  hipMemsetAsync(counts, 0, (size_t)N_NODES * sizeof(int), stream);
  prep_node_k<<<1026, 256, 0, stream>>>(x, sq, sq64, xf, W2, w2f, W1, w1cf);
  knn1_k<<<N_NODES / 64, 256, 0, stream>>>(xf, sq, candk);
  knn2_k<<<N_NODES / 128, 256, 0, stream>>>(x, sq64, candk, nbr, counts);
  scan_k<<<1, 1024, 0, stream>>>(counts, cursor);
  scatter_k<<<NEDGE / 256, 256, 0, stream>>>(nbr, cursor, srow, scol);
  prep_pq_k<<<N_NODES / 128, 256, 0, stream>>>(xf, w1cf, b1, PQ16);
  gemm2_k<<<2048, 256, 0, stream>>>(PQ16, srow, scol, w2f, b2, out);
  final_k<<<2048, 256, 0, stream>>>(out, counts);
}

// Round 22
// 488.785 us; speedup vs baseline: 1.1491x; 1.1491x over previous
//
#include <hip/hip_runtime.h>

typedef __attribute__((ext_vector_type(4))) float f32x4;
typedef __attribute__((ext_vector_type(4))) unsigned int u32x4;
typedef __attribute__((ext_vector_type(8))) short s16x8;
typedef __attribute__((ext_vector_type(8))) _Float16 f16x8;

#define N_NODES 65536
#define GNPG 1024
#define FDIM 64
#define HDIM 128
#define KNN 16
#define JT 64      // knn j-tile
#define DSTR 68    // knn key LDS row stride (u32)
#define SCAND 20   // per-subset candidate list (2 subsets/center)
#define STKC 6     // per-lane survivor stack depth (u32 keys)
#define NEDGE (N_NODES * KNN)
#define NT (NEDGE / 64)

// Per-node precompute (blocks 0..1023) + W2 frag prep (block 1024) + Wc frag prep (1025).
__global__ void prep_node_k(const float* __restrict__ x, float* __restrict__ sq,
                            double* __restrict__ sq64, _Float16* __restrict__ xf,
                            const float* __restrict__ W2, _Float16* __restrict__ w2f,
                            const float* __restrict__ W1, _Float16* __restrict__ w1cf) {
  if (blockIdx.x >= 1024) {
    int tid = threadIdx.x;
    if (blockIdx.x == 1024) {
      for (int idx = tid; idx < 8 * 4 * 64 * 8; idx += 256) {
        int j = idx & 7, l = (idx >> 3) & 63, ks = (idx >> 9) & 3, ct = idx >> 11;
        int k = 8 * (l >> 4) + j + 32 * ks, col = ct * 16 + (l & 15);
        w2f[idx] = (_Float16)W2[k * 128 + col];
      }
    } else {
      // Wc = [W1_top - W1_bot | W1_bot] (64x256) in B-frag order (16 ct x 2 ks).
      for (int idx = tid; idx < 16 * 2 * 64 * 8; idx += 256) {
        int j = idx & 7, l = (idx >> 3) & 63, ks = (idx >> 9) & 1, ct = idx >> 10;
        int k = 8 * (l >> 4) + j + 32 * ks, col = ct * 16 + (l & 15);
        float v = (col < 128) ? (W1[k * 128 + col] - W1[(k + 64) * 128 + col])
                              : W1[(k + 64) * 128 + (col - 128)];
        w1cf[idx] = (_Float16)v;
      }
    }
    return;
  }
  int t = blockIdx.x * 256 + threadIdx.x;
  int n = t >> 2, q = t & 3;
  const f32x4* xp = (const f32x4*)(x + (size_t)n * FDIM + q * 16);
  double s = 0;
  f16x8 h0, h1;
#pragma unroll
  for (int c8 = 0; c8 < 2; ++c8) {
    f32x4 a = xp[2 * c8], b = xp[2 * c8 + 1];
    f16x8 h;
#pragma unroll
    for (int e = 0; e < 4; ++e) {
      h[e] = (_Float16)a[e];
      h[4 + e] = (_Float16)b[e];
      s = fma((double)a[e], (double)a[e], s);
      s = fma((double)b[e], (double)b[e], s);
    }
    if (c8 == 0) h0 = h; else h1 = h;
  }
  *(f16x8*)(xf + (size_t)n * FDIM + q * 16) = h0;
  *(f16x8*)(xf + (size_t)n * FDIM + q * 16 + 8) = h1;
  s += __shfl_xor(s, 1);
  s += __shfl_xor(s, 2);
  if (q == 0) { sq64[n] = s; sq[n] = (float)s; }
}

// GEMM1 via fp16 MFMA: PQ16 = xf @ Wc (+b1 on cols>=128). 128 nodes/block, 4 waves.
__global__ __launch_bounds__(256) void prep_pq_k(const _Float16* __restrict__ xf,
                                                 const _Float16* __restrict__ w1cf,
                                                 const float* __restrict__ b1,
                                                 _Float16* __restrict__ PQ16) {
  __shared__ __attribute__((aligned(16))) _Float16 wcL[16384];   // 32KB
  int tid = threadIdx.x, lane = tid & 63, wave = tid >> 6;
  for (int i = tid; i < 2048; i += 256)
    *(f16x8*)(wcL + i * 8) = *(const f16x8*)(w1cf + i * 8);
  int rbase = blockIdx.x * 128 + wave * 32;
  f16x8 af[2][2];
#pragma unroll
  for (int rt = 0; rt < 2; ++rt)
#pragma unroll
    for (int ks = 0; ks < 2; ++ks) {
      size_t off = (size_t)(rbase + rt * 16 + (lane & 15)) * FDIM + (lane >> 4) * 8 + 32 * ks;
      af[rt][ks] = *(const f16x8*)(xf + off);
    }
  __syncthreads();
  f32x4 acc[2][16];
#pragma unroll
  for (int rt = 0; rt < 2; ++rt)
#pragma unroll
    for (int ct = 0; ct < 16; ++ct) acc[rt][ct] = (f32x4){0.f, 0.f, 0.f, 0.f};
#pragma unroll
  for (int ks = 0; ks < 2; ++ks)
#pragma unroll
    for (int ct = 0; ct < 16; ++ct) {
      f16x8 b = *(const f16x8*)(wcL + ((ct * 2 + ks) * 64 + lane) * 8);
#pragma unroll
      for (int rt = 0; rt < 2; ++rt)
        acc[rt][ct] = __builtin_amdgcn_mfma_f32_16x16x32_f16(af[rt][ks], b, acc[rt][ct], 0, 0, 0);
    }
  float b1r[16];
#pragma unroll
  for (int ct = 0; ct < 16; ++ct)
    b1r[ct] = (ct >= 8) ? b1[(ct - 8) * 16 + (lane & 15)] : 0.f;
#pragma unroll
  for (int rt = 0; rt < 2; ++rt)
#pragma unroll
    for (int ct = 0; ct < 16; ++ct) {
      int col = ct * 16 + (lane & 15);
#pragma unroll
      for (int r = 0; r < 4; ++r) {
        int row = rbase + rt * 16 + (lane >> 4) * 4 + r;
        PQ16[(size_t)row * 256 + col] = (_Float16)(acc[rt][ct][r] + b1r[ct]);
      }
    }
}

// KNN stage 1 (r17/r20 proven form + XCD co-location): graph g's 8 blocks all have
// blockIdx % 8 == g % 8 -> same XCD L2 holds the graph's xf. fp16 MFMA distances,
// biased-positive monotone u32 keys, streaming survivor-stack scan + joint drains.
__global__ __launch_bounds__(256) void knn1_k(const _Float16* __restrict__ xf,
                                              const float* __restrict__ sq,
                                              unsigned short* __restrict__ candi) {
  __shared__ float sq_l[GNPG];
  __shared__ __attribute__((aligned(16))) _Float16 bfL[512 * 8];
  __shared__ __attribute__((aligned(16))) unsigned keyL[128 * DSTR];
  __shared__ __attribute__((aligned(16))) unsigned stk[STKC * 256];
  int tid = threadIdx.x, lane = tid & 63, wave = tid >> 6;
  int g = blockIdx.x & 63;            // XCD co-location: all 8 blocks of graph g share blockIdx%8
  int rb = (blockIdx.x >> 6) * 128;
  const _Float16* xfg = xf + (size_t)g * GNPG * FDIM;
  for (int i = tid; i < GNPG; i += 256) sq_l[i] = sq[g * GNPG + i] + 0.5f;  // d' = d + 1 > 0
  f16x8 af[2][2];
#pragma unroll
  for (int rt = 0; rt < 2; ++rt)
#pragma unroll
    for (int ks = 0; ks < 2; ++ks) {
      size_t off = (size_t)(rb + wave * 32 + rt * 16 + (lane & 15)) * FDIM + (lane >> 4) * 8 + 32 * ks;
      af[rt][ks] = *(const f16x8*)(xfg + off);
    }
  unsigned dl[SCAND];
#pragma unroll
  for (int q = 0; q < SCAND; ++q) dl[q] = 0xFFFFFFFFu;
  int c = tid >> 1, sub = tid & 1;
  int sp = 0;
  for (int jt = 0; jt < GNPG / JT; ++jt) {
#pragma unroll
    for (int s2 = tid; s2 < 512; s2 += 256) {
      int ct = s2 >> 7, ks = (s2 >> 6) & 1, l = s2 & 63;
      size_t goff = (size_t)(jt * JT + ct * 16 + (l & 15)) * FDIM + (l >> 4) * 8 + 32 * ks;
      *(f16x8*)(bfL + s2 * 8) = *(const f16x8*)(xfg + goff);
    }
    __syncthreads();
    f32x4 acc[2][4];
#pragma unroll
    for (int rt = 0; rt < 2; ++rt)
#pragma unroll
      for (int ct = 0; ct < 4; ++ct) acc[rt][ct] = (f32x4){0.f, 0.f, 0.f, 0.f};
#pragma unroll
    for (int ks = 0; ks < 2; ++ks)
#pragma unroll
      for (int ct = 0; ct < 4; ++ct) {
        f16x8 bfr = *(const f16x8*)(bfL + ((ct * 2 + ks) * 64 + lane) * 8);
#pragma unroll
        for (int rt = 0; rt < 2; ++rt)
          acc[rt][ct] = __builtin_amdgcn_mfma_f32_16x16x32_f16(af[rt][ks], bfr, acc[rt][ct], 0, 0, 0);
      }
#pragma unroll
    for (int rt = 0; rt < 2; ++rt)
#pragma unroll
      for (int ct = 0; ct < 4; ++ct) {
        int coltl = ct * 16 + (lane & 15);
        int jlg = jt * JT + coltl;
        float sqj = sq_l[jlg];
#pragma unroll
        for (int r = 0; r < 4; ++r) {
          int row = wave * 32 + rt * 16 + (lane >> 4) * 4 + r;
          float d = sq_l[rb + row] + sqj - 2.f * acc[rt][ct][r];   // > 0 (biased)
          unsigned key = (__float_as_uint(d) & 0xFFFFFC00u) | (unsigned)jlg;
          if (rb + row == jlg) key = 0xFFFFFFFFu;
          keyL[row * DSTR + coltl] = key;
        }
      }
    __syncthreads();
    const unsigned* kp = keyL + c * DSTR + sub * 32;
#pragma unroll 2
    for (int i = 0; i < 8; ++i) {
      if (__any(sp > STKC - 4)) {
        while (__any(sp > 0)) {
          if (sp > 0) {
            --sp;
            unsigned k = stk[sp * 256 + tid];
            if (k < dl[SCAND - 1]) {
              dl[SCAND - 1] = k;
#pragma unroll
              for (int p = SCAND - 1; p >= 1; --p) {
                unsigned mn = min(dl[p - 1], dl[p]);
                unsigned mx = max(dl[p - 1], dl[p]);
                dl[p - 1] = mn; dl[p] = mx;
              }
            }
          }
        }
      }
      u32x4 v = *(const u32x4*)(kp + i * 4);
#pragma unroll
      for (int e = 0; e < 4; ++e) {
        stk[sp * 256 + tid] = v[e];
        sp += (v[e] < dl[SCAND - 1]) ? 1 : 0;
      }
    }
  }
  while (__any(sp > 0)) {
    if (sp > 0) {
      --sp;
      unsigned k = stk[sp * 256 + tid];
      if (k < dl[SCAND - 1]) {
        dl[SCAND - 1] = k;
#pragma unroll
        for (int p = SCAND - 1; p >= 1; --p) {
          unsigned mn = min(dl[p - 1], dl[p]);
          unsigned mx = max(dl[p - 1], dl[p]);
          dl[p - 1] = mn; dl[p] = mx;
        }
      }
    }
  }
  int nglob = g * GNPG + rb + c;
  unsigned short* ii = candi + (size_t)nglob * (2 * SCAND) + sub * SCAND;
#pragma unroll
  for (int q = 0; q < SCAND; ++q) ii[q] = (unsigned short)(dl[q] & 1023u);
}

// KNN stage 2 (+ XCD co-location): 2 threads/center, f64 rescore of own sub's 20
// (unroll-1, immediate-consume loads), 16-deep (d64,idx) ladder, LDS 2-pointer merge.
__global__ __launch_bounds__(256) void knn2_k(const float* __restrict__ x,
                                              const double* __restrict__ sq64,
                                              const unsigned short* __restrict__ candi,
                                              int* __restrict__ nbr, int* __restrict__ counts) {
  __shared__ double md[2][128][17];
  __shared__ unsigned short mi[2][128][17];
  int tid = threadIdx.x, c_local = tid >> 1, sub = tid & 1;
  int cb = (blockIdx.x & 63) * 8 + (blockIdx.x >> 6);   // graph = cb/8 ≡ blockIdx%8 (mod 8)
  int n = cb * 128 + c_local;
  int gbase = n & ~(GNPG - 1);
  f32x4 xi[16];
  const f32x4* xp = (const f32x4*)(x + (size_t)n * FDIM);
#pragma unroll
  for (int f = 0; f < 16; ++f) xi[f] = xp[f];
  double sq64i = sq64[n];
  double dl[KNN]; int il[KNN];
#pragma unroll
  for (int q = 0; q < KNN; ++q) { dl[q] = 1.0e300; il[q] = 0x7FFFFFFF; }
  const unsigned short* ii = candi + (size_t)n * (2 * SCAND) + sub * SCAND;
#pragma unroll 1
  for (int t = 0; t < SCAND; ++t) {
    int jl = ii[t];
    int j = gbase + jl;
    const f32x4* xj = (const f32x4*)(x + (size_t)j * FDIM);
    double t0 = 0, t1 = 0, t2 = 0, t3 = 0;
#pragma unroll
    for (int f = 0; f < 16; ++f) {
      f32x4 a = xi[f], b = xj[f];
      t0 = fma((double)a[0], (double)b[0], t0);
      t1 = fma((double)a[1], (double)b[1], t1);
      t2 = fma((double)a[2], (double)b[2], t2);
      t3 = fma((double)a[3], (double)b[3], t3);
    }
    double d = sq64i + sq64[j] - 2.0 * ((t0 + t1) + (t2 + t3));
    bool ins = (d < dl[KNN - 1]) || (d == dl[KNN - 1] && jl < il[KNN - 1]);
    if (ins) {
      dl[KNN - 1] = d; il[KNN - 1] = jl;
#pragma unroll
      for (int p = KNN - 1; p >= 1; --p) {
        double a0 = dl[p - 1], a1 = dl[p];
        int b0 = il[p - 1], b1v = il[p];
        bool cc = (a1 < a0) || (a1 == a0 && b1v < b0);
        dl[p - 1] = cc ? a1 : a0; dl[p] = cc ? a0 : a1;
        il[p - 1] = cc ? b1v : b0; il[p] = cc ? b0 : b1v;
      }
    }
  }
#pragma unroll
  for (int q = 0; q < KNN; ++q) {
    md[sub][c_local][q] = dl[q];
    mi[sub][c_local][q] = (unsigned short)il[q];
  }
  __syncthreads();
  if (sub == 0) {
    int pa = 0, pb = 0;
    for (int q = 0; q < KNN; ++q) {
      double da = md[0][c_local][pa]; int ia = mi[0][c_local][pa];
      double db = md[1][c_local][pb]; int ib = mi[1][c_local][pb];
      bool tb = (db < da) || (db == da && ib < ia);
      int iw = tb ? ib : ia;
      pa += !tb; pb += tb;
      int gidx = gbase + iw;
      nbr[(size_t)n * KNN + q] = gidx;
      atomicAdd(&counts[gidx], 1);
    }
  }
}

// Block-wide scan: 1024 threads x 64 counts, shfl wave-scan + wave partials.
__global__ void scan_k(const int* __restrict__ counts, int* __restrict__ cursor) {
  __shared__ int wsum[16];
  int t = threadIdx.x;
  int base = t * 64;
  const int4* cp = (const int4*)(counts + base);
  int s = 0;
#pragma unroll
  for (int i = 0; i < 16; ++i) { int4 v = cp[i]; s += v.x + v.y + v.z + v.w; }
  int lane = t & 63, wv = t >> 6;
  int pre = s;
#pragma unroll
  for (int ofs = 1; ofs < 64; ofs <<= 1) {
    int o = __shfl_up(pre, ofs);
    if (lane >= ofs) pre += o;
  }
  if (lane == 63) wsum[wv] = pre;
  __syncthreads();
  if (t == 0) {
    int run = 0;
#pragma unroll
    for (int i = 0; i < 16; ++i) { int v = wsum[i]; wsum[i] = run; run += v; }
  }
  __syncthreads();
  int run = wsum[wv] + pre - s;
#pragma unroll
  for (int i = 0; i < 16; ++i) {
    int4 v = cp[i];
    cursor[base + 4 * i] = run; run += v.x;
    cursor[base + 4 * i + 1] = run; run += v.y;
    cursor[base + 4 * i + 2] = run; run += v.z;
    cursor[base + 4 * i + 3] = run; run += v.w;
  }
}

__global__ void scatter_k(const int* __restrict__ nbr, int* __restrict__ cursor,
                          int* __restrict__ srow, int* __restrict__ scol) {
  int e = blockIdx.x * 256 + threadIdx.x;
  int r = nbr[e], c = e >> 4;
  int pos = atomicAdd(&cursor[r], 1);
  srow[pos] = r; scol[pos] = c;
}

// gemm2 (r12 proven form + srowL staging + XCD tile swizzle): each XCD processes only
// tiles of graphs ≡ XCD (mod 8) -> PQ16 gathers and out atomics are L2-local.
__global__ __launch_bounds__(256) void gemm2_k(const _Float16* __restrict__ PQ16,
                                               const int* __restrict__ srow, const int* __restrict__ scol,
                                               const _Float16* __restrict__ w2f,
                                               const float* __restrict__ b2,
                                               float* __restrict__ out) {
  __shared__ __attribute__((aligned(16))) char smem[16384];
  __shared__ int srowL[64];
  int tid = threadIdx.x, lane = tid & 63, wave = tid >> 6;
  int cg = wave & 1, eg = wave >> 1;
  int bswz = (blockIdx.x & 7) * 256 + (blockIdx.x >> 3);   // graph(tile) ≡ blockIdx%8 (mod 8)
  f16x8 wf[4][4];
#pragma unroll
  for (int ct = 0; ct < 4; ++ct)
#pragma unroll
    for (int ks = 0; ks < 4; ++ks)
      wf[ct][ks] = *(const f16x8*)(w2f + ((((cg * 4 + ct) * 4 + ks) * 64 + lane) * 8));
  float b2r[4];
#pragma unroll
  for (int ct = 0; ct < 4; ++ct) b2r[ct] = b2[cg * 64 + ct * 16 + (lane & 15)];

  int e_in = tid >> 2, qq = tid & 3;
  f16x8 pf[8];
  int prow;
  {
    int e = bswz * 64 + e_in;
    prow = srow[e];
    int colc = scol[e];
    const f16x8* Pp = (const f16x8*)(PQ16 + (size_t)prow * 256 + qq * 32);
    const f16x8* Qp = (const f16x8*)(PQ16 + (size_t)colc * 256 + 128 + qq * 32);
#pragma unroll
    for (int i = 0; i < 4; ++i) { pf[i] = Pp[i]; pf[4 + i] = Qp[i]; }
  }
  for (int tile = bswz; tile < NT; tile += gridDim.x) {
    if (qq == 0) srowL[e_in] = prow;
#pragma unroll
    for (int i = 0; i < 4; ++i) {
      f16x8 hv;
#pragma unroll
      for (int e = 0; e < 8; ++e) {
        float sv = (float)pf[i][e] + (float)pf[4 + i][e];
        hv[e] = (_Float16)(sv > 0.f ? sv : 0.f);
      }
      int byteoff = e_in * 256 + ((2 * (qq * 32 + i * 8)) ^ ((e_in & 7) << 4));
      *(f16x8*)(smem + byteoff) = hv;
    }
    int ntile = tile + gridDim.x;
    if (ntile < NT) {
      int e = ntile * 64 + e_in;
      prow = srow[e];
      int colc = scol[e];
      const f16x8* Pp = (const f16x8*)(PQ16 + (size_t)prow * 256 + qq * 32);
      const f16x8* Qp = (const f16x8*)(PQ16 + (size_t)colc * 256 + 128 + qq * 32);
#pragma unroll
      for (int i = 0; i < 4; ++i) { pf[i] = Pp[i]; pf[4 + i] = Qp[i]; }
    }
    __syncthreads();   // A + srowL visible
    f32x4 acc[2][4];
#pragma unroll
    for (int rt = 0; rt < 2; ++rt)
#pragma unroll
      for (int ct = 0; ct < 4; ++ct) acc[rt][ct] = (f32x4){0.f, 0.f, 0.f, 0.f};
#pragma unroll
    for (int rt = 0; rt < 2; ++rt) {
      int rowL = eg * 32 + rt * 16 + (lane & 15);
#pragma unroll
      for (int ks = 0; ks < 4; ++ks) {
        int byteoff = rowL * 256 + ((16 * (lane >> 4) + 64 * ks) ^ ((rowL & 7) << 4));
        f16x8 a = *(const f16x8*)(smem + byteoff);
#pragma unroll
        for (int ct = 0; ct < 4; ++ct)
          acc[rt][ct] = __builtin_amdgcn_mfma_f32_16x16x32_f16(a, wf[ct][ks], acc[rt][ct], 0, 0, 0);
      }
    }
    __syncthreads();   // A consumed; smem becomes h2 (fp16 [64][128], (row&12)<<3 swizzle)
#pragma unroll
    for (int rt = 0; rt < 2; ++rt)
#pragma unroll
      for (int ct = 0; ct < 4; ++ct) {
        int col = cg * 64 + ct * 16 + (lane & 15);
#pragma unroll
        for (int r = 0; r < 4; ++r) {
          int row_in = eg * 32 + rt * 16 + (lane >> 4) * 4 + r;
          float v = acc[rt][ct][r] + b2r[ct];
          v = v > 0.f ? v : 0.f;
          int byteoff = row_in * 256 + ((2 * col) ^ ((row_in & 12) << 3));
          *(_Float16*)(smem + byteoff) = (_Float16)v;
        }
      }
    __syncthreads();   // h2 visible
    {
      int col = tid & 127, estart = (tid >> 7) * 32;
      float a = 0.f;
      int prev = srowL[estart];
#pragma unroll 8
      for (int e2 = estart; e2 < estart + 32; ++e2) {
        int r2 = srowL[e2];
        if (r2 != prev) { atomicAdd(out + (size_t)prev * 128 + col, a); a = 0.f; prev = r2; }
        int byteoff = e2 * 256 + ((2 * col) ^ ((e2 & 12) << 3));
        a += (float)*(const _Float16*)(smem + byteoff);
      }
      atomicAdd(out + (size_t)prev * 128 + col, a);
    }
    __syncthreads();   // h2 + srowL consumed before next stage write
  }
}

__global__ void final_k(float* __restrict__ out, const int* __restrict__ counts) {
  for (int i = blockIdx.x * 256 + threadIdx.x; i < N_NODES * 32; i += gridDim.x * 256) {
    f32x4 v = ((f32x4*)out)[i];
    int n = i >> 5;
    int c = counts[n];
    float inv = 1.0f / (float)(c > 0 ? c : 1);
    v[0] *= inv; v[1] *= inv; v[2] *= inv; v[3] *= inv;
    ((f32x4*)out)[i] = v;
  }
}

extern "C" void kernel_launch(void* const* d_in, const int* in_sizes, int n_in,
                              void* d_out, int out_size, void* d_ws, size_t ws_size,
                              hipStream_t stream) {
  const float* x = (const float*)d_in[0];
  const float* W1 = (const float*)d_in[2];
  const float* b1 = (const float*)d_in[3];
  const float* W2 = (const float*)d_in[4];
  const float* b2 = (const float*)d_in[5];
  float* out = (float*)d_out;
  char* ws = (char*)d_ws;

  // No aliasing: PQ16 [0,32M); xf [32M,40M); candi [40M,45.2M); rest as before.
  _Float16* PQ16 = (_Float16*)(ws + 0);                    // 33,554,432 B
  _Float16* xf = (_Float16*)(ws + 33554432);               //  8,388,608 B
  unsigned short* candi = (unsigned short*)(ws + 41943040);//  5,242,880 B (end 47,185,920)
  float* sq = (float*)(ws + 67108864);                     //    262,144 B
  int* nbr = (int*)(ws + 67371008);                        //  4,194,304 B
  int* counts = (int*)(ws + 71565312);                     //    262,144 B
  int* cursor = (int*)(ws + 71827456);                     //    262,144 B
  int* srow = (int*)(ws + 72089600);                       //  4,194,304 B
  int* scol = (int*)(ws + 76283904);                       //  4,194,304 B
  _Float16* w2f = (_Float16*)(ws + 80478208);              //     32,768 B
  _Float16* w1cf = (_Float16*)(ws + 80510976);             //     32,768 B
  double* sq64 = (double*)(ws + 80543744);                 //    524,288 B  (end 81,068,032)

  hipMemsetAsync(d_out, 0, (size_t)out_size * sizeof(float), stream);
  hipMemsetAsync(counts, 0, (size_t)N_NODES * sizeof(int), stream);
  prep_node_k<<<1026, 256, 0, stream>>>(x, sq, sq64, xf, W2, w2f, W1, w1cf);
  knn1_k<<<N_NODES / 128, 256, 0, stream>>>(xf, sq, candi);
  knn2_k<<<N_NODES / 128, 256, 0, stream>>>(x, sq64, candi, nbr, counts);
  scan_k<<<1, 1024, 0, stream>>>(counts, cursor);
  scatter_k<<<NEDGE / 256, 256, 0, stream>>>(nbr, cursor, srow, scol);
  prep_pq_k<<<N_NODES / 128, 256, 0, stream>>>(xf, w1cf, b1, PQ16);
  gemm2_k<<<2048, 256, 0, stream>>>(PQ16, srow, scol, w2f, b2, out);
  final_k<<<2048, 256, 0, stream>>>(out, counts);
}